// Round 1
// baseline (293.288 us; speedup 1.0000x reference)
//
#include <hip/hip_runtime.h>

#define IN_DIM  16
#define HID_DIM 64
#define OUT_DIM 32

// ---------------------------------------------------------------------------
// Edge dtype handling: reference declares int64, harness doc says int32.
// Detect at runtime: nonneg int64 < 2^31 has every odd 32-bit word == 0.
// ---------------------------------------------------------------------------
__device__ __forceinline__ long long edge_at(const void* edges, int is64, long long i) {
    if (is64) return ((const long long*)edges)[i];
    return (long long)((const int*)edges)[i];
}

__global__ void k_detect_dtype(const void* edges, int* flag) {
    if (threadIdx.x == 0 && blockIdx.x == 0) {
        const int* w = (const int*)edges;
        int is64 = 1;
        for (int i = 0; i < 16; ++i) {
            if (w[2 * i + 1] != 0) { is64 = 0; break; }
        }
        *flag = is64;
    }
}

// deg[i] = 1.0 (self-loop contribution to degree)
__global__ void k_init_deg(float* deg, long long N) {
    long long i = blockIdx.x * 256LL + threadIdx.x;
    if (i < N) deg[i] = 1.0f;
}

// deg[dst[e]] += 1 for each real edge
__global__ void k_degree(const void* edges, const int* flag, float* deg, long long E) {
    long long e = blockIdx.x * 256LL + threadIdx.x;
    if (e >= E) return;
    long long d = edge_at(edges, *flag, E + e);
    atomicAdd(&deg[d], 1.0f);
}

// in-place: deg -> rsqrt(deg); deg >= 1 always (self-loops) so no zero guard needed
__global__ void k_dinv(float* deg, long long N) {
    long long i = blockIdx.x * 256LL + threadIdx.x;
    if (i < N) deg[i] = rsqrtf(deg[i]);
}

// aggX[i][c] = x[i][c] * dinv[i]^2   (self-loop message, also serves as init)
__global__ void k_init_aggx(const float* __restrict__ x, const float* __restrict__ dinv,
                            float* __restrict__ aggX, long long total) {
    long long j = blockIdx.x * 256LL + threadIdx.x;
    if (j >= total) return;
    float dv = dinv[j >> 4];   // j / IN_DIM
    aggX[j] = x[j] * dv * dv;
}

// layer-1 scatter over raw features: aggX[dst][c] += x[src][c] * dinv[src]*dinv[dst]
__global__ void k_scatter1(const void* edges, const int* flag,
                           const float* __restrict__ x, const float* __restrict__ dinv,
                           float* __restrict__ aggX, long long E) {
    long long tid = blockIdx.x * 256LL + threadIdx.x;
    long long e = tid >> 4;
    if (e >= E) return;
    int c = (int)(tid & 15);
    int is64 = *flag;
    long long s = edge_at(edges, is64, e);
    long long d = edge_at(edges, is64, E + e);
    float nrm = dinv[s] * dinv[d];
    atomicAdd(&aggX[d * IN_DIM + c], x[s * IN_DIM + c] * nrm);
}

// h1 = relu(aggX @ W1 + b1)   [N,16] @ [16,64]
__global__ void k_gemm1_relu(const float* __restrict__ aggX, const float* __restrict__ W1,
                             const float* __restrict__ b1, float* __restrict__ h1, long long N) {
    __shared__ float Ws[IN_DIM * HID_DIM];   // 4 KB
    __shared__ float Xs[4][IN_DIM];
    int tid = threadIdx.x;
    for (int i = tid; i < IN_DIM * HID_DIM; i += 256) Ws[i] = W1[i];
    long long node0 = blockIdx.x * 4LL;
    if (tid < 64) {
        int r = tid >> 4, c = tid & 15;
        long long node = node0 + r;
        Xs[r][c] = (node < N) ? aggX[node * IN_DIM + c] : 0.f;
    }
    __syncthreads();
    int col = tid & 63, r = tid >> 6;
    long long node = node0 + r;
    if (node < N) {
        float acc = b1[col];
        #pragma unroll
        for (int k = 0; k < IN_DIM; ++k) acc += Xs[r][k] * Ws[k * HID_DIM + col];
        h1[node * HID_DIM + col] = fmaxf(acc, 0.f);
    }
}

// h2 = h1 @ W2   [N,64] @ [64,32]
__global__ void k_gemm2(const float* __restrict__ h1, const float* __restrict__ W2,
                        float* __restrict__ h2, long long N) {
    __shared__ float Ws[HID_DIM * OUT_DIM];  // 8 KB
    __shared__ float Xs[8][HID_DIM];
    int tid = threadIdx.x;
    for (int i = tid; i < HID_DIM * OUT_DIM; i += 256) Ws[i] = W2[i];
    long long node0 = blockIdx.x * 8LL;
    for (int i = tid; i < 8 * HID_DIM; i += 256) {
        int r = i >> 6, c = i & 63;
        long long node = node0 + r;
        Xs[r][c] = (node < N) ? h1[node * HID_DIM + c] : 0.f;
    }
    __syncthreads();
    int col = tid & 31, r = tid >> 5;
    long long node = node0 + r;
    if (node < N) {
        float acc = 0.f;
        #pragma unroll
        for (int k = 0; k < HID_DIM; ++k) acc += Xs[r][k] * Ws[k * OUT_DIM + col];
        h2[node * OUT_DIM + col] = acc;
    }
}

// out[i][c] = h2[i][c] * dinv[i]^2 + b2[c]   (self-loop + bias, also init)
__global__ void k_init_out(const float* __restrict__ h2, const float* __restrict__ dinv,
                           const float* __restrict__ b2, float* __restrict__ out, long long total) {
    long long j = blockIdx.x * 256LL + threadIdx.x;
    if (j >= total) return;
    float dv = dinv[j >> 5];   // j / OUT_DIM
    out[j] = h2[j] * dv * dv + b2[j & 31];
}

// layer-2 scatter: out[dst][c] += h2[src][c] * dinv[src]*dinv[dst]
__global__ void k_scatter2(const void* edges, const int* flag,
                           const float* __restrict__ h2, const float* __restrict__ dinv,
                           float* __restrict__ out, long long E) {
    long long tid = blockIdx.x * 256LL + threadIdx.x;
    long long e = tid >> 5;
    if (e >= E) return;
    int c = (int)(tid & 31);
    int is64 = *flag;
    long long s = edge_at(edges, is64, e);
    long long d = edge_at(edges, is64, E + e);
    float nrm = dinv[s] * dinv[d];
    atomicAdd(&out[d * OUT_DIM + c], h2[s * OUT_DIM + c] * nrm);
}

extern "C" void kernel_launch(void* const* d_in, const int* in_sizes, int n_in,
                              void* d_out, int out_size, void* d_ws, size_t ws_size,
                              hipStream_t stream) {
    const float* x     = (const float*)d_in[0];
    const void*  edges = d_in[1];
    const float* W1    = (const float*)d_in[2];
    const float* b1    = (const float*)d_in[3];
    const float* W2    = (const float*)d_in[4];
    const float* b2    = (const float*)d_in[5];
    float* out = (float*)d_out;

    const long long N = in_sizes[0] / IN_DIM;   // 50000
    const long long E = in_sizes[1] / 2;        // 800000 (dtype-independent: element count)

    // workspace layout (floats): [deg/dinv: N][aggX: 16N][h1: 64N][h2: 32N][flag: 1 int]
    float* f    = (float*)d_ws;
    float* deg  = f;                 // becomes dinv in place
    float* aggX = deg + N;
    float* h1   = aggX + IN_DIM * N;
    float* h2   = h1 + HID_DIM * N;
    int*   flag = (int*)(h2 + OUT_DIM * N);

    const int B = 256;
    k_detect_dtype<<<1, 1, 0, stream>>>(edges, flag);
    k_init_deg<<<(int)((N + B - 1) / B), B, 0, stream>>>(deg, N);
    k_degree<<<(int)((E + B - 1) / B), B, 0, stream>>>(edges, flag, deg, E);
    k_dinv<<<(int)((N + B - 1) / B), B, 0, stream>>>(deg, N);

    const long long aggx_total = N * IN_DIM;
    k_init_aggx<<<(int)((aggx_total + B - 1) / B), B, 0, stream>>>(x, deg, aggX, aggx_total);

    const long long s1_total = E * IN_DIM;
    k_scatter1<<<(int)((s1_total + B - 1) / B), B, 0, stream>>>(edges, flag, x, deg, aggX, E);

    k_gemm1_relu<<<(int)((N + 3) / 4), B, 0, stream>>>(aggX, W1, b1, h1, N);
    k_gemm2<<<(int)((N + 7) / 8), B, 0, stream>>>(h1, W2, h2, N);

    const long long out_total = N * OUT_DIM;
    k_init_out<<<(int)((out_total + B - 1) / B), B, 0, stream>>>(h2, deg, b2, out, out_total);

    const long long s2_total = E * OUT_DIM;
    k_scatter2<<<(int)((s2_total + B - 1) / B), B, 0, stream>>>(edges, flag, h2, deg, out, E);
}